// Round 8
// baseline (346.749 us; speedup 1.0000x reference)
//
#include <hip/hip_runtime.h>
#include <hip/hip_bf16.h>
#include <cstdint>

// Problem constants (fixed by reference)
#define NN 100000
#define HH 96
#define AD 32
#define DE 16
#define EE 500000
#define NEG 0.01f

// Bucketing: 98 buckets of 1024 nodes per edge type
#define GSH 10
#define GSZ 1024
#define KB 98
#define CH 4096
#define BPT 123   // ceil(EE/CH)

typedef __bf16 bf16x8 __attribute__((ext_vector_type(8)));
typedef float  f32x4  __attribute__((ext_vector_type(4)));

__device__ __forceinline__ unsigned short f2b(float x) {
    union { float f; unsigned int u; } v; v.f = x;
    unsigned int r = v.u + 0x7fffu + ((v.u >> 16) & 1u);  // RNE
    return (unsigned short)(r >> 16);
}
__device__ __forceinline__ float b2f(unsigned short h) {
    union { unsigned int u; float f; } v; v.u = ((unsigned int)h) << 16;
    return v.f;
}

// ---------------------------------------------------------------------------
// prep: cvec[3][96], wvec[4][96], B-fragment-swizzled bf16 weights.
// BfN: 6 sections (S0,S1,S2,D0,D1,D2) x 3 ksteps x 6 colblocks x 64 lanes x 8
//   (S = Wm rows 0..95 [src part], D = Wm rows 96..191 [dst part])
// BfU: 12 ksteps x 6 colblocks x 64 lanes x 8   (Wu 384x96)
// B-frag for mfma_f32_16x16x32_bf16: lane = ((k%32)/8)*16 + (n%16), j = k%8
// ---------------------------------------------------------------------------
__global__ void prep_kernel(const float* Wm0, const float* bm0, const float* ef0,
                            const float* Wm1, const float* bm1, const float* ef1,
                            const float* Wm2, const float* bm2, const float* ef2,
                            const float* Wn0, const float* Wa0,
                            const float* Wn1, const float* Wa1,
                            const float* Wu,
                            float* cvec, float* wvec,
                            unsigned short* BfN, unsigned short* BfU) {
    const float* Wm[3] = {Wm0, Wm1, Wm2};
    const float* bm[3] = {bm0, bm1, bm2};
    const float* ef[3] = {ef0, ef1, ef2};
    const int total = 288 + 384 + 55296 + 36864;
    for (int i = blockIdx.x * blockDim.x + threadIdx.x; i < total;
         i += gridDim.x * blockDim.x) {
        if (i < 288) {
            int t = i / 96, j = i % 96;
            float s = bm[t][j];
            for (int k = 0; k < DE; ++k) s += ef[t][k] * Wm[t][(2 * HH + k) * HH + j];
            cvec[i] = s;
        } else if (i < 288 + 384) {
            int ii = i - 288;
            int kind = ii / 96, k = ii % 96;
            const float* Wn = (kind < 2) ? Wn0 : Wn1;
            const float* Wa = (kind < 2) ? Wa0 : Wa1;
            int off = (kind & 1) ? AD : 0;
            float s = 0.f;
            for (int a = 0; a < AD; ++a) s += Wn[k * AD + a] * Wa[off + a];
            wvec[ii] = s;
        } else if (i < 288 + 384 + 55296) {
            int ii = i - 672;
            int sec = ii / 9216; int rem = ii % 9216;
            int ksc = rem / 512; int lj = rem % 512;
            int ks = ksc / 6, c = ksc % 6;
            int lane = lj / 8, jj = lj % 8;
            int quad = lane / 16, m = lane % 16;
            int k = ks * 32 + quad * 8 + jj;
            int n = c * 16 + m;
            int mt = (sec < 3) ? sec : sec - 3;
            int rowoff = (sec < 3) ? 0 : HH;
            BfN[ii] = f2b(Wm[mt][(rowoff + k) * HH + n]);
        } else {
            int ii = i - (672 + 55296);
            int ksc = ii / 512; int lj = ii % 512;
            int ks = ksc / 6, c = ksc % 6;
            int lane = lj / 8, jj = lj % 8;
            int quad = lane / 16, m = lane % 16;
            int k = ks * 32 + quad * 8 + jj;
            int n = c * 16 + m;
            BfU[ii] = f2b(Wu[k * HH + n]);
        }
    }
}

// Fused: bf16 cast of h + u/v attention pre-dots. One 32-lane group per node.
__global__ void cast_uv_kernel(const float* __restrict__ h, const float* __restrict__ wvec,
                               unsigned short* __restrict__ hb, float* __restrict__ uv) {
    int lane = threadIdx.x & 31;
    int node = (blockIdx.x * blockDim.x + threadIdx.x) >> 5;
    if (node >= NN) return;
    float h0 = h[node * HH + lane];
    float h1 = h[node * HH + 32 + lane];
    float h2 = h[node * HH + 64 + lane];
    hb[node * HH + lane] = f2b(h0);
    hb[node * HH + 32 + lane] = f2b(h1);
    hb[node * HH + 64 + lane] = f2b(h2);
    float acc[4];
#pragma unroll
    for (int q = 0; q < 4; ++q)
        acc[q] = h0 * wvec[q * 96 + lane] + h1 * wvec[q * 96 + 32 + lane] +
                 h2 * wvec[q * 96 + 64 + lane];
#pragma unroll
    for (int d = 16; d >= 1; d >>= 1)
#pragma unroll
        for (int q = 0; q < 4; ++q) acc[q] += __shfl_down(acc[q], d, 32);
    if (lane == 0) {
#pragma unroll
        for (int q = 0; q < 4; ++q) uv[q * NN + node] = acc[q];
    }
}

__global__ void zero_kernel(float4* __restrict__ p, int n4) {
    for (int i = blockIdx.x * blockDim.x + threadIdx.x; i < n4;
         i += gridDim.x * blockDim.x)
        p[i] = make_float4(0.f, 0.f, 0.f, 0.f);
}

// ---------------------------------------------------------------------------
// Two-level CSR build: bucket hist -> scan -> LDS-ranked scatter (line-dense
// runs) -> per-bucket counting sort confined to one CU's L2 span.
// bucket_sort additionally precomputes per-edge attention weights expw.
// ---------------------------------------------------------------------------
__global__ void bucket_hist(const int* __restrict__ d0, const int* __restrict__ d1,
                            const int* __restrict__ d2, int* __restrict__ bCnt) {
    __shared__ int hist[3 * KB];
    int t = threadIdx.x;
    for (int j = t; j < 3 * KB; j += 256) hist[j] = 0;
    __syncthreads();
    const int total = 3 * EE;
    for (int i = blockIdx.x * blockDim.x + t; i < total; i += gridDim.x * blockDim.x) {
        int ty = i / EE, e = i - ty * EE;
        const int* d = (ty == 0) ? d0 : (ty == 1) ? d1 : d2;
        atomicAdd(&hist[ty * KB + (d[e] >> GSH)], 1);
    }
    __syncthreads();
    for (int j = t; j < 3 * KB; j += 256)
        if (hist[j]) atomicAdd(&bCnt[j], hist[j]);
}

__global__ void bucket_scan(const int* __restrict__ bCnt, int* __restrict__ bBase,
                            int* __restrict__ gCursor, int* __restrict__ rs) {
    __shared__ int hist[3 * KB];
    int t = threadIdx.x;
    if (t < 3 * KB) hist[t] = bCnt[t];
    __syncthreads();
    if (t < 3) {
        int run = 0;
        for (int b = 0; b < KB; ++b) {
            bBase[t * (KB + 1) + b] = run;
            gCursor[t * KB + b] = run;
            run += hist[t * KB + b];
        }
        bBase[t * (KB + 1) + KB] = run;           // == EE
        rs[(size_t)t * (NN + 1) + NN] = run;
    }
}

__global__ __launch_bounds__(256) void bucket_scatter(
    const int* __restrict__ s0, const int* __restrict__ d0,
    const int* __restrict__ s1, const int* __restrict__ d1,
    const int* __restrict__ s2, const int* __restrict__ d2,
    int* __restrict__ gCursor, unsigned int* __restrict__ binned) {
    __shared__ unsigned int recs[CH];
    __shared__ unsigned short rnk[CH];
    __shared__ unsigned char bkt[CH];
    __shared__ int cnt[KB];
    __shared__ int gpos[KB];
    int t = threadIdx.x;
    int type = blockIdx.x / BPT;
    int chunk = (blockIdx.x % BPT) * CH;
    const int* src = (type == 0) ? s0 : (type == 1) ? s1 : s2;
    const int* dst = (type == 0) ? d0 : (type == 1) ? d1 : d2;
    if (t < KB) cnt[t] = 0;
    __syncthreads();
#pragma unroll
    for (int k = 0; k < CH / 256; ++k) {
        int idx = k * 256 + t;
        int e = chunk + idx;
        if (e < EE) {
            int s = src[e], d = dst[e];
            int b = d >> GSH;
            recs[idx] = ((unsigned int)s << GSH) | (unsigned int)(d & (GSZ - 1));
            bkt[idx] = (unsigned char)b;
            rnk[idx] = (unsigned short)atomicAdd(&cnt[b], 1);
        } else {
            bkt[idx] = 0xFF;
        }
    }
    __syncthreads();
    if (t < KB) {
        int c = cnt[t];
        gpos[t] = (c > 0) ? atomicAdd(&gCursor[type * KB + t], c) : 0;
    }
    __syncthreads();
    unsigned int* bout = binned + (size_t)type * EE;
#pragma unroll
    for (int k = 0; k < CH / 256; ++k) {
        int idx = k * 256 + t;
        unsigned char b = bkt[idx];
        if (b != 0xFF) bout[gpos[b] + rnk[idx]] = recs[idx];
    }
}

__global__ __launch_bounds__(256) void bucket_sort(
    const unsigned int* __restrict__ binned, const int* __restrict__ bBase,
    const float* __restrict__ uv,
    int* __restrict__ rs, int* __restrict__ sorted, float* __restrict__ expw) {
    __shared__ int cnt[GSZ];
    __shared__ int tsum[256];
    int t = threadIdx.x;
    int type = blockIdx.x / KB;
    int b = blockIdx.x % KB;
    int nodeBase = b * GSZ;
    int eb = bBase[type * (KB + 1) + b];
    int en = bBase[type * (KB + 1) + b + 1];
    int n = en - eb;
    const unsigned int* bin = binned + (size_t)type * EE + eb;
#pragma unroll
    for (int k = 0; k < GSZ / 256; ++k) cnt[k * 256 + t] = 0;
    __syncthreads();
    for (int i = t; i < n; i += 256) atomicAdd(&cnt[bin[i] & (GSZ - 1)], 1);
    __syncthreads();
    int v[4], s = 0;
#pragma unroll
    for (int k = 0; k < 4; ++k) { v[k] = cnt[t * 4 + k]; s += v[k]; }
    tsum[t] = s;
    __syncthreads();
    for (int off = 1; off < 256; off <<= 1) {
        int add = (t >= off) ? tsum[t - off] : 0;
        __syncthreads();
        tsum[t] += add;
        __syncthreads();
    }
    int run = tsum[t] - s;  // exclusive base for this thread's 4 nodes
    int offk[4];
#pragma unroll
    for (int k = 0; k < 4; ++k) { offk[k] = run; run += v[k]; }
    int* rsrow = rs + (size_t)type * (NN + 1) + nodeBase;
#pragma unroll
    for (int k = 0; k < 4; ++k) {
        int node = t * 4 + k;
        if (nodeBase + node < NN) rsrow[node] = eb + offk[k];
    }
    __syncthreads();  // all cnt reads done before overwrite
#pragma unroll
    for (int k = 0; k < 4; ++k) cnt[t * 4 + k] = offk[k];
    __syncthreads();
    int* so = sorted + (size_t)type * EE + eb;
    float* ew = expw + (size_t)type * EE + eb;
    const float* u = uv + 2 * type * NN;
    const float* vv = uv + (2 * type + 1) * NN;
    for (int i = t; i < n; i += 256) {
        unsigned int r = bin[i];
        int dl = r & (GSZ - 1);
        int p = atomicAdd(&cnt[dl], 1);
        int srcn = (int)(r >> GSH);
        so[p] = srcn;
        float wgt = 1.f;
        if (type < 2) {
            float sc = u[srcn] + vv[nodeBase + dl];
            sc = sc > 0.f ? sc : NEG * sc;
            wgt = __expf(sc);
        }
        ew[p] = wgt;
    }
}

// All-type h-space gather aggregation in ONE launch: grid (12500, 3).
// Weights precomputed in bucket_sort (expw); inner loop is pure gather+FMA.
// hagg_t[d] = (sum w_e h[src_e]) / sum w_e.
__global__ void aggregate_kernel(const int* __restrict__ rsAll, const int* __restrict__ sortedAll,
                                 const float* __restrict__ expwAll,
                                 const unsigned short* __restrict__ hb,
                                 unsigned short* __restrict__ hagg,
                                 float* __restrict__ den) {
    const size_t NH = (size_t)NN * HH;
    int lane = threadIdx.x & 31;
    int node = (blockIdx.x * blockDim.x + threadIdx.x) >> 5;
    if (node >= NN) return;
    int t = blockIdx.y;
    const int* rs = rsAll + (size_t)t * (NN + 1);
    const int* sorted = sortedAll + (size_t)t * EE;
    const float* expw = expwAll + (size_t)t * EE;

    int beg = rs[node], end = rs[node + 1];
    float a0 = 0.f, a1 = 0.f, a2 = 0.f, dn = 0.f;
    for (int base = beg; base < end; base += 32) {
        int batch = end - base;
        if (batch > 32) batch = 32;
        int li = lane < batch ? lane : batch - 1;
        int myS = sorted[base + li];
        float myW = expw[base + li];
#pragma unroll 1
        for (int j = 0; j < batch; j += 8) {
            int rem = batch - j;
            int sI[8];
            float wv[8];
#pragma unroll
            for (int k = 0; k < 8; ++k) {
                int jj = (k < rem ? j + k : j);
                sI[k] = __shfl(myS, jj, 32);
                wv[k] = __shfl(myW, jj, 32);
            }
#pragma unroll
            for (int k = 0; k < 8; ++k) if (k >= rem) wv[k] = 0.f;
            float x0[8], x1[8], x2[8];
#pragma unroll
            for (int k = 0; k < 8; ++k) {
                const unsigned short* pr = hb + (size_t)sI[k] * HH;
                x0[k] = b2f(pr[lane]);
                x1[k] = b2f(pr[lane + 32]);
                x2[k] = b2f(pr[lane + 64]);
            }
#pragma unroll
            for (int k = 0; k < 8; ++k) {
                dn += wv[k];
                a0 += wv[k] * x0[k];
                a1 += wv[k] * x1[k];
                a2 += wv[k] * x2[k];
            }
        }
    }
    float r0 = 0.f, r1 = 0.f, r2 = 0.f;
    if (dn > 0.f) {
        float inv = 1.f / dn;
        r0 = a0 * inv; r1 = a1 * inv; r2 = a2 * inv;
    }
    unsigned short* mr = hagg + (size_t)t * NH + (size_t)node * HH;
    mr[lane] = f2b(r0);
    mr[lane + 32] = f2b(r1);
    mr[lane + 64] = f2b(r2);
    if (lane == 0) den[(size_t)t * NN + node] = dn;
}

// Fused msg + update GEMM. Per wave: 16 rows.
// Phase 1: msg_t = z_t*(hagg_t@WmS_t + h@WmD_t + c_t) -> LDS tile (16x288, pad 296)
// Phase 2: out = relu([h | msg] @ Wu + bu), A-frags from regs (h) and LDS (msg).
#define MSP 296
__global__ __launch_bounds__(256) void fused_update_kernel(
    const unsigned short* __restrict__ hagg, const unsigned short* __restrict__ hb,
    const unsigned short* __restrict__ BfN, const unsigned short* __restrict__ BfU,
    const float* __restrict__ den, const float* __restrict__ cvec,
    const float* __restrict__ bu, float* __restrict__ out) {
    __shared__ unsigned short msgt[4][16][MSP];
    const size_t NH = (size_t)NN * HH;
    int wave = threadIdx.x >> 6;
    int lane = threadIdx.x & 63;
    int quad = lane >> 4, m = lane & 15;
    int blk = blockIdx.x * 4 + wave;
    bool active = (blk < NN / 16);
    int r0 = blk * 16;
    bf16x8 hfrag[3];
    if (active) {
        const unsigned short* hrow = hb + (size_t)(r0 + m) * HH + quad * 8;
#pragma unroll
        for (int ks = 0; ks < 3; ++ks) hfrag[ks] = *(const bf16x8*)(hrow + ks * 32);
#pragma unroll
        for (int t = 0; t < 3; ++t) {
            f32x4 acc[6] = {};
            const unsigned short* harow = hagg + (size_t)t * NH + (size_t)(r0 + m) * HH + quad * 8;
#pragma unroll
            for (int ks = 0; ks < 3; ++ks) {
                bf16x8 af = *(const bf16x8*)(harow + ks * 32);
#pragma unroll
                for (int c = 0; c < 6; ++c) {
                    bf16x8 bfv = *(const bf16x8*)(BfN + (((t * 3 + ks) * 6 + c) << 9) + lane * 8);
                    acc[c] = __builtin_amdgcn_mfma_f32_16x16x32_bf16(af, bfv, acc[c], 0, 0, 0);
                }
            }
#pragma unroll
            for (int ks = 0; ks < 3; ++ks) {
#pragma unroll
                for (int c = 0; c < 6; ++c) {
                    bf16x8 bfv = *(const bf16x8*)(BfN + ((((t + 3) * 3 + ks) * 6 + c) << 9) + lane * 8);
                    acc[c] = __builtin_amdgcn_mfma_f32_16x16x32_bf16(hfrag[ks], bfv, acc[c], 0, 0, 0);
                }
            }
            float dnv[4];
#pragma unroll
            for (int r = 0; r < 4; ++r) dnv[r] = den[(size_t)t * NN + r0 + quad * 4 + r];
#pragma unroll
            for (int c = 0; c < 6; ++c) {
                float cv = cvec[t * 96 + c * 16 + m];
#pragma unroll
                for (int r = 0; r < 4; ++r) {
                    float val = (dnv[r] > 0.f) ? (acc[c][r] + cv) : 0.f;
                    msgt[wave][quad * 4 + r][t * 96 + c * 16 + m] = f2b(val);
                }
            }
        }
    }
    __syncthreads();
    if (active) {
        f32x4 acc2[6] = {};
#pragma unroll
        for (int ks = 0; ks < 12; ++ks) {
            bf16x8 af = (ks < 3) ? hfrag[ks]
                                 : *(const bf16x8*)&msgt[wave][m][(ks - 3) * 32 + quad * 8];
#pragma unroll
            for (int c = 0; c < 6; ++c) {
                bf16x8 bfv = *(const bf16x8*)(BfU + ((ks * 6 + c) << 9) + lane * 8);
                acc2[c] = __builtin_amdgcn_mfma_f32_16x16x32_bf16(af, bfv, acc2[c], 0, 0, 0);
            }
        }
#pragma unroll
        for (int c = 0; c < 6; ++c) {
            float b = bu[c * 16 + m];
#pragma unroll
            for (int r = 0; r < 4; ++r) {
                int row = r0 + quad * 4 + r;
                float v2 = acc2[c][r] + b;
                out[(size_t)row * HH + c * 16 + m] = v2 > 0.f ? v2 : 0.f;
            }
        }
    }
}

extern "C" void kernel_launch(void* const* d_in, const int* in_sizes, int n_in,
                              void* d_out, int out_size, void* d_ws, size_t ws_size,
                              hipStream_t stream) {
    (void)in_sizes; (void)n_in; (void)out_size;
    const float* h   = (const float*)d_in[0];
    const int* srcs[3] = {(const int*)d_in[1], (const int*)d_in[3], (const int*)d_in[5]};
    const int* dsts[3] = {(const int*)d_in[2], (const int*)d_in[4], (const int*)d_in[6]};
    const float* Wm0 = (const float*)d_in[7];
    const float* bm0 = (const float*)d_in[8];
    const float* ef0 = (const float*)d_in[9];
    const float* Wm1 = (const float*)d_in[10];
    const float* bm1 = (const float*)d_in[11];
    const float* ef1 = (const float*)d_in[12];
    const float* Wm2 = (const float*)d_in[13];
    const float* bm2 = (const float*)d_in[14];
    const float* ef2 = (const float*)d_in[15];
    const float* Wn0 = (const float*)d_in[16];
    const float* Wa0 = (const float*)d_in[17];
    const float* Wn1 = (const float*)d_in[18];
    const float* Wa1 = (const float*)d_in[19];
    const float* Wu  = (const float*)d_in[20];
    const float* bu  = (const float*)d_in[21];
    float* out = (float*)d_out;

    // Workspace layout (total ~99 MB; ws_size measured 256 MiB in round 5)
    const size_t NEED = 98991104;
    if (ws_size < NEED) return;  // fail validation cleanly instead of faulting
    char* w = (char*)d_ws;
    unsigned short* hb      = (unsigned short*)(w + 0);            // N*96 bf16
    unsigned short* hagg    = (unsigned short*)(w + 19200000);     // 3*N*96 bf16
    float*          den     = (float*)(w + 76800000);              // 3*N f32
    float*          uv      = (float*)(w + 78000000);              // 4*N f32
    float*          cvec    = (float*)(w + 79600000);              // 288 f32
    float*          wvec    = (float*)(w + 79601280);              // 384 f32
    unsigned short* BfN     = (unsigned short*)(w + 79602816);     // 55296 bf16
    unsigned short* BfU     = (unsigned short*)(w + 79713408);     // 36864 bf16
    int*            bBase   = (int*)(w + 79787136);                // 3*(KB+1) int
    int*            gCursor = (int*)(w + 79788416);                // 3*KB int
    int*            bCnt    = (int*)(w + 79789696);                // 3*KB int
    int*            rs      = (int*)(w + 79790976);                // 3*(N+1) int
    int*            sorted  = (int*)(w + 80991104);                // 3*E int
    unsigned int*   binned  = (unsigned int*)(w + 86991104);       // 3*E u32
    float*          expw    = (float*)(w + 92991104);              // 3*E f32

    prep_kernel<<<128, 256, 0, stream>>>(Wm0, bm0, ef0, Wm1, bm1, ef1, Wm2, bm2, ef2,
                                         Wn0, Wa0, Wn1, Wa1, Wu, cvec, wvec, BfN, BfU);
    cast_uv_kernel<<<12500, 256, 0, stream>>>(h, wvec, hb, uv);

    // CSR build for all 3 edge types (bucketed two-level sort, fused edge weights)
    zero_kernel<<<1, 256, 0, stream>>>((float4*)bCnt, 80);
    bucket_hist<<<512, 256, 0, stream>>>(dsts[0], dsts[1], dsts[2], bCnt);
    bucket_scan<<<1, 384, 0, stream>>>(bCnt, bBase, gCursor, rs);
    bucket_scatter<<<3 * BPT, 256, 0, stream>>>(srcs[0], dsts[0], srcs[1], dsts[1],
                                                srcs[2], dsts[2], gCursor, binned);
    bucket_sort<<<3 * KB, 256, 0, stream>>>(binned, bBase, uv, rs, sorted, expw);

    aggregate_kernel<<<dim3(12500, 3), 256, 0, stream>>>(rs, sorted, expw, hb, hagg, den);
    fused_update_kernel<<<1563, 256, 0, stream>>>(hagg, hb, BfN, BfU, den, cvec, bu, out);
}

// Round 9
// 335.427 us; speedup vs baseline: 1.0338x; 1.0338x over previous
//
#include <hip/hip_runtime.h>
#include <hip/hip_bf16.h>
#include <cstdint>

// Problem constants (fixed by reference)
#define NN 100000
#define HH 96
#define AD 32
#define DE 16
#define EE 500000
#define NEG 0.01f

// Bucketing: 98 buckets of 1024 nodes per edge type
#define GSH 10
#define GSZ 1024
#define KB 98
#define CH 4096
#define BPT 123   // ceil(EE/CH)

typedef __bf16 bf16x8 __attribute__((ext_vector_type(8)));
typedef float  f32x4  __attribute__((ext_vector_type(4)));

__device__ __forceinline__ unsigned short f2b(float x) {
    union { float f; unsigned int u; } v; v.f = x;
    unsigned int r = v.u + 0x7fffu + ((v.u >> 16) & 1u);  // RNE
    return (unsigned short)(r >> 16);
}
__device__ __forceinline__ float b2f(unsigned short h) {
    union { unsigned int u; float f; } v; v.u = ((unsigned int)h) << 16;
    return v.f;
}

// ---------------------------------------------------------------------------
// prep: cvec[3][96], wvec[4][96], B-fragment-swizzled bf16 weights.
// BfN: 6 sections (S0,S1,S2,D0,D1,D2) x 3 ksteps x 6 colblocks x 64 lanes x 8
//   (S = Wm rows 0..95 [src part], D = Wm rows 96..191 [dst part])
// BfU: 12 ksteps x 6 colblocks x 64 lanes x 8   (Wu 384x96)
// B-frag for mfma_f32_16x16x32_bf16: lane = ((k%32)/8)*16 + (n%16), j = k%8
// ---------------------------------------------------------------------------
__global__ void prep_kernel(const float* Wm0, const float* bm0, const float* ef0,
                            const float* Wm1, const float* bm1, const float* ef1,
                            const float* Wm2, const float* bm2, const float* ef2,
                            const float* Wn0, const float* Wa0,
                            const float* Wn1, const float* Wa1,
                            const float* Wu,
                            float* cvec, float* wvec,
                            unsigned short* BfN, unsigned short* BfU) {
    const float* Wm[3] = {Wm0, Wm1, Wm2};
    const float* bm[3] = {bm0, bm1, bm2};
    const float* ef[3] = {ef0, ef1, ef2};
    const int total = 288 + 384 + 55296 + 36864;
    for (int i = blockIdx.x * blockDim.x + threadIdx.x; i < total;
         i += gridDim.x * blockDim.x) {
        if (i < 288) {
            int t = i / 96, j = i % 96;
            float s = bm[t][j];
            for (int k = 0; k < DE; ++k) s += ef[t][k] * Wm[t][(2 * HH + k) * HH + j];
            cvec[i] = s;
        } else if (i < 288 + 384) {
            int ii = i - 288;
            int kind = ii / 96, k = ii % 96;
            const float* Wn = (kind < 2) ? Wn0 : Wn1;
            const float* Wa = (kind < 2) ? Wa0 : Wa1;
            int off = (kind & 1) ? AD : 0;
            float s = 0.f;
            for (int a = 0; a < AD; ++a) s += Wn[k * AD + a] * Wa[off + a];
            wvec[ii] = s;
        } else if (i < 288 + 384 + 55296) {
            int ii = i - 672;
            int sec = ii / 9216; int rem = ii % 9216;
            int ksc = rem / 512; int lj = rem % 512;
            int ks = ksc / 6, c = ksc % 6;
            int lane = lj / 8, jj = lj % 8;
            int quad = lane / 16, m = lane % 16;
            int k = ks * 32 + quad * 8 + jj;
            int n = c * 16 + m;
            int mt = (sec < 3) ? sec : sec - 3;
            int rowoff = (sec < 3) ? 0 : HH;
            BfN[ii] = f2b(Wm[mt][(rowoff + k) * HH + n]);
        } else {
            int ii = i - (672 + 55296);
            int ksc = ii / 512; int lj = ii % 512;
            int ks = ksc / 6, c = ksc % 6;
            int lane = lj / 8, jj = lj % 8;
            int quad = lane / 16, m = lane % 16;
            int k = ks * 32 + quad * 8 + jj;
            int n = c * 16 + m;
            BfU[ii] = f2b(Wu[k * HH + n]);
        }
    }
}

// Fused: bf16 cast of h + u/v attention pre-dots. One 32-lane group per node.
__global__ void cast_uv_kernel(const float* __restrict__ h, const float* __restrict__ wvec,
                               unsigned short* __restrict__ hb, float* __restrict__ uv) {
    int lane = threadIdx.x & 31;
    int node = (blockIdx.x * blockDim.x + threadIdx.x) >> 5;
    if (node >= NN) return;
    float h0 = h[node * HH + lane];
    float h1 = h[node * HH + 32 + lane];
    float h2 = h[node * HH + 64 + lane];
    hb[node * HH + lane] = f2b(h0);
    hb[node * HH + 32 + lane] = f2b(h1);
    hb[node * HH + 64 + lane] = f2b(h2);
    float acc[4];
#pragma unroll
    for (int q = 0; q < 4; ++q)
        acc[q] = h0 * wvec[q * 96 + lane] + h1 * wvec[q * 96 + 32 + lane] +
                 h2 * wvec[q * 96 + 64 + lane];
#pragma unroll
    for (int d = 16; d >= 1; d >>= 1)
#pragma unroll
        for (int q = 0; q < 4; ++q) acc[q] += __shfl_down(acc[q], d, 32);
    if (lane == 0) {
#pragma unroll
        for (int q = 0; q < 4; ++q) uv[q * NN + node] = acc[q];
    }
}

__global__ void zero_kernel(float4* __restrict__ p, int n4) {
    for (int i = blockIdx.x * blockDim.x + threadIdx.x; i < n4;
         i += gridDim.x * blockDim.x)
        p[i] = make_float4(0.f, 0.f, 0.f, 0.f);
}

// ---------------------------------------------------------------------------
// Two-level CSR build: bucket hist -> scan -> LDS-ranked scatter (line-dense
// runs) -> per-bucket counting sort confined to one CU's L2 span.
// bucket_sort additionally precomputes per-edge attention weights expw.
// ---------------------------------------------------------------------------
__global__ void bucket_hist(const int* __restrict__ d0, const int* __restrict__ d1,
                            const int* __restrict__ d2, int* __restrict__ bCnt) {
    __shared__ int hist[3 * KB];
    int t = threadIdx.x;
    for (int j = t; j < 3 * KB; j += 256) hist[j] = 0;
    __syncthreads();
    const int total = 3 * EE;
    for (int i = blockIdx.x * blockDim.x + t; i < total; i += gridDim.x * blockDim.x) {
        int ty = i / EE, e = i - ty * EE;
        const int* d = (ty == 0) ? d0 : (ty == 1) ? d1 : d2;
        atomicAdd(&hist[ty * KB + (d[e] >> GSH)], 1);
    }
    __syncthreads();
    for (int j = t; j < 3 * KB; j += 256)
        if (hist[j]) atomicAdd(&bCnt[j], hist[j]);
}

__global__ void bucket_scan(const int* __restrict__ bCnt, int* __restrict__ bBase,
                            int* __restrict__ gCursor, int* __restrict__ rs) {
    __shared__ int hist[3 * KB];
    int t = threadIdx.x;
    if (t < 3 * KB) hist[t] = bCnt[t];
    __syncthreads();
    if (t < 3) {
        int run = 0;
        for (int b = 0; b < KB; ++b) {
            bBase[t * (KB + 1) + b] = run;
            gCursor[t * KB + b] = run;
            run += hist[t * KB + b];
        }
        bBase[t * (KB + 1) + KB] = run;           // == EE
        rs[(size_t)t * (NN + 1) + NN] = run;
    }
}

__global__ __launch_bounds__(256) void bucket_scatter(
    const int* __restrict__ s0, const int* __restrict__ d0,
    const int* __restrict__ s1, const int* __restrict__ d1,
    const int* __restrict__ s2, const int* __restrict__ d2,
    int* __restrict__ gCursor, unsigned int* __restrict__ binned) {
    __shared__ unsigned int recs[CH];
    __shared__ unsigned short rnk[CH];
    __shared__ unsigned char bkt[CH];
    __shared__ int cnt[KB];
    __shared__ int gpos[KB];
    int t = threadIdx.x;
    int type = blockIdx.x / BPT;
    int chunk = (blockIdx.x % BPT) * CH;
    const int* src = (type == 0) ? s0 : (type == 1) ? s1 : s2;
    const int* dst = (type == 0) ? d0 : (type == 1) ? d1 : d2;
    if (t < KB) cnt[t] = 0;
    __syncthreads();
#pragma unroll
    for (int k = 0; k < CH / 256; ++k) {
        int idx = k * 256 + t;
        int e = chunk + idx;
        if (e < EE) {
            int s = src[e], d = dst[e];
            int b = d >> GSH;
            recs[idx] = ((unsigned int)s << GSH) | (unsigned int)(d & (GSZ - 1));
            bkt[idx] = (unsigned char)b;
            rnk[idx] = (unsigned short)atomicAdd(&cnt[b], 1);
        } else {
            bkt[idx] = 0xFF;
        }
    }
    __syncthreads();
    if (t < KB) {
        int c = cnt[t];
        gpos[t] = (c > 0) ? atomicAdd(&gCursor[type * KB + t], c) : 0;
    }
    __syncthreads();
    unsigned int* bout = binned + (size_t)type * EE;
#pragma unroll
    for (int k = 0; k < CH / 256; ++k) {
        int idx = k * 256 + t;
        unsigned char b = bkt[idx];
        if (b != 0xFF) bout[gpos[b] + rnk[idx]] = recs[idx];
    }
}

__global__ __launch_bounds__(256) void bucket_sort(
    const unsigned int* __restrict__ binned, const int* __restrict__ bBase,
    const float* __restrict__ uv,
    int* __restrict__ rs, int* __restrict__ sorted, float* __restrict__ expw) {
    __shared__ int cnt[GSZ];
    __shared__ int tsum[256];
    int t = threadIdx.x;
    int type = blockIdx.x / KB;
    int b = blockIdx.x % KB;
    int nodeBase = b * GSZ;
    int eb = bBase[type * (KB + 1) + b];
    int en = bBase[type * (KB + 1) + b + 1];
    int n = en - eb;
    const unsigned int* bin = binned + (size_t)type * EE + eb;
#pragma unroll
    for (int k = 0; k < GSZ / 256; ++k) cnt[k * 256 + t] = 0;
    __syncthreads();
    for (int i = t; i < n; i += 256) atomicAdd(&cnt[bin[i] & (GSZ - 1)], 1);
    __syncthreads();
    int v[4], s = 0;
#pragma unroll
    for (int k = 0; k < 4; ++k) { v[k] = cnt[t * 4 + k]; s += v[k]; }
    tsum[t] = s;
    __syncthreads();
    for (int off = 1; off < 256; off <<= 1) {
        int add = (t >= off) ? tsum[t - off] : 0;
        __syncthreads();
        tsum[t] += add;
        __syncthreads();
    }
    int run = tsum[t] - s;  // exclusive base for this thread's 4 nodes
    int offk[4];
#pragma unroll
    for (int k = 0; k < 4; ++k) { offk[k] = run; run += v[k]; }
    int* rsrow = rs + (size_t)type * (NN + 1) + nodeBase;
#pragma unroll
    for (int k = 0; k < 4; ++k) {
        int node = t * 4 + k;
        if (nodeBase + node < NN) rsrow[node] = eb + offk[k];
    }
    __syncthreads();  // all cnt reads done before overwrite
#pragma unroll
    for (int k = 0; k < 4; ++k) cnt[t * 4 + k] = offk[k];
    __syncthreads();
    int* so = sorted + (size_t)type * EE + eb;
    float* ew = expw + (size_t)type * EE + eb;
    const float* u = uv + 2 * type * NN;
    const float* vv = uv + (2 * type + 1) * NN;
    for (int i = t; i < n; i += 256) {
        unsigned int r = bin[i];
        int dl = r & (GSZ - 1);
        int p = atomicAdd(&cnt[dl], 1);
        int srcn = (int)(r >> GSH);
        so[p] = srcn;
        float wgt = 1.f;
        if (type < 2) {
            float sc = u[srcn] + vv[nodeBase + dl];
            sc = sc > 0.f ? sc : NEG * sc;
            wgt = __expf(sc);
        }
        ew[p] = wgt;
    }
}

// All-type h-space gather aggregation in ONE launch: grid (12500, 3).
// Weights precomputed in bucket_sort (expw); inner loop is pure gather+FMA.
// hagg_t[d] = (sum w_e h[src_e]) / sum w_e.
__global__ void aggregate_kernel(const int* __restrict__ rsAll, const int* __restrict__ sortedAll,
                                 const float* __restrict__ expwAll,
                                 const unsigned short* __restrict__ hb,
                                 unsigned short* __restrict__ hagg,
                                 float* __restrict__ den) {
    const size_t NH = (size_t)NN * HH;
    int lane = threadIdx.x & 31;
    int node = (blockIdx.x * blockDim.x + threadIdx.x) >> 5;
    if (node >= NN) return;
    int t = blockIdx.y;
    const int* rs = rsAll + (size_t)t * (NN + 1);
    const int* sorted = sortedAll + (size_t)t * EE;
    const float* expw = expwAll + (size_t)t * EE;

    int beg = rs[node], end = rs[node + 1];
    float a0 = 0.f, a1 = 0.f, a2 = 0.f, dn = 0.f;
    for (int base = beg; base < end; base += 32) {
        int batch = end - base;
        if (batch > 32) batch = 32;
        int li = lane < batch ? lane : batch - 1;
        int myS = sorted[base + li];
        float myW = expw[base + li];
#pragma unroll 1
        for (int j = 0; j < batch; j += 8) {
            int rem = batch - j;
            int sI[8];
            float wv[8];
#pragma unroll
            for (int k = 0; k < 8; ++k) {
                int jj = (k < rem ? j + k : j);
                sI[k] = __shfl(myS, jj, 32);
                wv[k] = __shfl(myW, jj, 32);
            }
#pragma unroll
            for (int k = 0; k < 8; ++k) if (k >= rem) wv[k] = 0.f;
            float x0[8], x1[8], x2[8];
#pragma unroll
            for (int k = 0; k < 8; ++k) {
                const unsigned short* pr = hb + (size_t)sI[k] * HH;
                x0[k] = b2f(pr[lane]);
                x1[k] = b2f(pr[lane + 32]);
                x2[k] = b2f(pr[lane + 64]);
            }
#pragma unroll
            for (int k = 0; k < 8; ++k) {
                dn += wv[k];
                a0 += wv[k] * x0[k];
                a1 += wv[k] * x1[k];
                a2 += wv[k] * x2[k];
            }
        }
    }
    float r0 = 0.f, r1 = 0.f, r2 = 0.f;
    if (dn > 0.f) {
        float inv = 1.f / dn;
        r0 = a0 * inv; r1 = a1 * inv; r2 = a2 * inv;
    }
    unsigned short* mr = hagg + (size_t)t * NH + (size_t)node * HH;
    mr[lane] = f2b(r0);
    mr[lane + 32] = f2b(r1);
    mr[lane + 64] = f2b(r2);
    if (lane == 0) den[(size_t)t * NN + node] = dn;
}

// msg_t = z_t * ( hagg_t @ WmS_t + h @ WmD_t + c_t ), K=192 MFMA, grid (1563,3).
// z_t = (den_t > 0) per row. Writes bf16 into msgb[:, t*96:(t+1)*96].
__global__ __launch_bounds__(256) void msg_gemm_kernel(const unsigned short* __restrict__ hagg,
                                                       const unsigned short* __restrict__ hb,
                                                       const unsigned short* __restrict__ BfN,
                                                       const float* __restrict__ den,
                                                       const float* __restrict__ cvec,
                                                       unsigned short* __restrict__ msgb) {
    const size_t NH = (size_t)NN * HH;
    int wave = threadIdx.x >> 6;
    int lane = threadIdx.x & 63;
    int quad = lane >> 4, m = lane & 15;
    int blk = blockIdx.x * 4 + wave;
    if (blk >= NN / 16) return;
    int t = blockIdx.y;
    int r0 = blk * 16;
    const unsigned short* ha = hagg + (size_t)t * NH;
    f32x4 acc[6] = {};
#pragma unroll
    for (int ks = 0; ks < 6; ++ks) {
        const unsigned short* ap =
            (ks < 3) ? ha + (size_t)(r0 + m) * HH + ks * 32 + quad * 8
                     : hb + (size_t)(r0 + m) * HH + (ks - 3) * 32 + quad * 8;
        int sec = (ks < 3) ? t : t + 3;
        int kk = (ks < 3) ? ks : ks - 3;
        bf16x8 af = *(const bf16x8*)ap;
#pragma unroll
        for (int c = 0; c < 6; ++c) {
            bf16x8 bfv = *(const bf16x8*)(BfN + (((sec * 3 + kk) * 6 + c) << 9) + lane * 8);
            acc[c] = __builtin_amdgcn_mfma_f32_16x16x32_bf16(af, bfv, acc[c], 0, 0, 0);
        }
    }
    float dn[4];
#pragma unroll
    for (int r = 0; r < 4; ++r) dn[r] = den[(size_t)t * NN + r0 + quad * 4 + r];
#pragma unroll
    for (int c = 0; c < 6; ++c) {
        float cv = cvec[t * 96 + c * 16 + m];
#pragma unroll
        for (int r = 0; r < 4; ++r) {
            int row = r0 + quad * 4 + r;
            float val = (dn[r] > 0.f) ? (acc[c][r] + cv) : 0.f;
            msgb[(size_t)row * 288 + t * 96 + c * 16 + m] = f2b(val);
        }
    }
}

// out = relu([h | msg] @ Wu + bu): M=100000, K=384, N=96
__global__ __launch_bounds__(256) void update_gemm_kernel(const unsigned short* __restrict__ hb,
                                                          const unsigned short* __restrict__ msgb,
                                                          const unsigned short* __restrict__ BfU,
                                                          const float* __restrict__ bu,
                                                          float* __restrict__ out) {
    int wave = threadIdx.x >> 6;
    int lane = threadIdx.x & 63;
    int quad = lane >> 4, m = lane & 15;
    int blk = blockIdx.x * 4 + wave;
    if (blk >= NN / 16) return;
    int r0 = blk * 16;
    f32x4 acc[6] = {};
#pragma unroll
    for (int ks = 0; ks < 12; ++ks) {
        const unsigned short* ap =
            (ks < 3) ? hb + (size_t)(r0 + m) * HH + ks * 32 + quad * 8
                     : msgb + (size_t)(r0 + m) * 288 + (ks - 3) * 32 + quad * 8;
        bf16x8 af = *(const bf16x8*)ap;
#pragma unroll
        for (int c = 0; c < 6; ++c) {
            bf16x8 bfv = *(const bf16x8*)(BfU + ((ks * 6 + c) << 9) + lane * 8);
            acc[c] = __builtin_amdgcn_mfma_f32_16x16x32_bf16(af, bfv, acc[c], 0, 0, 0);
        }
    }
#pragma unroll
    for (int c = 0; c < 6; ++c) {
        float b = bu[c * 16 + m];
#pragma unroll
        for (int r = 0; r < 4; ++r) {
            int row = r0 + quad * 4 + r;
            float v2 = acc[c][r] + b;
            out[(size_t)row * HH + c * 16 + m] = v2 > 0.f ? v2 : 0.f;
        }
    }
}

extern "C" void kernel_launch(void* const* d_in, const int* in_sizes, int n_in,
                              void* d_out, int out_size, void* d_ws, size_t ws_size,
                              hipStream_t stream) {
    (void)in_sizes; (void)n_in; (void)out_size;
    const float* h   = (const float*)d_in[0];
    const int* srcs[3] = {(const int*)d_in[1], (const int*)d_in[3], (const int*)d_in[5]};
    const int* dsts[3] = {(const int*)d_in[2], (const int*)d_in[4], (const int*)d_in[6]};
    const float* Wm0 = (const float*)d_in[7];
    const float* bm0 = (const float*)d_in[8];
    const float* ef0 = (const float*)d_in[9];
    const float* Wm1 = (const float*)d_in[10];
    const float* bm1 = (const float*)d_in[11];
    const float* ef1 = (const float*)d_in[12];
    const float* Wm2 = (const float*)d_in[13];
    const float* bm2 = (const float*)d_in[14];
    const float* ef2 = (const float*)d_in[15];
    const float* Wn0 = (const float*)d_in[16];
    const float* Wa0 = (const float*)d_in[17];
    const float* Wn1 = (const float*)d_in[18];
    const float* Wa1 = (const float*)d_in[19];
    const float* Wu  = (const float*)d_in[20];
    const float* bu  = (const float*)d_in[21];
    float* out = (float*)d_out;

    // Workspace layout (total ~157 MB; ws_size measured 256 MiB in round 5)
    const size_t NEED = 156591104;
    if (ws_size < NEED) return;  // fail validation cleanly instead of faulting
    char* w = (char*)d_ws;
    unsigned short* hb      = (unsigned short*)(w + 0);            // N*96 bf16
    unsigned short* hagg    = (unsigned short*)(w + 19200000);     // 3*N*96 bf16
    unsigned short* msgb    = (unsigned short*)(w + 76800000);     // N*288 bf16
    float*          den     = (float*)(w + 134400000);             // 3*N f32
    float*          uv      = (float*)(w + 135600000);             // 4*N f32
    float*          cvec    = (float*)(w + 137200000);             // 288 f32
    float*          wvec    = (float*)(w + 137201280);             // 384 f32
    unsigned short* BfN     = (unsigned short*)(w + 137202816);    // 55296 bf16
    unsigned short* BfU     = (unsigned short*)(w + 137313408);    // 36864 bf16
    int*            bBase   = (int*)(w + 137387136);               // 3*(KB+1) int
    int*            gCursor = (int*)(w + 137388416);               // 3*KB int
    int*            bCnt    = (int*)(w + 137389696);               // 3*KB int
    int*            rs      = (int*)(w + 137390976);               // 3*(N+1) int
    int*            sorted  = (int*)(w + 138591104);               // 3*E int
    unsigned int*   binned  = (unsigned int*)(w + 144591104);      // 3*E u32
    float*          expw    = (float*)(w + 150591104);             // 3*E f32

    prep_kernel<<<128, 256, 0, stream>>>(Wm0, bm0, ef0, Wm1, bm1, ef1, Wm2, bm2, ef2,
                                         Wn0, Wa0, Wn1, Wa1, Wu, cvec, wvec, BfN, BfU);
    cast_uv_kernel<<<12500, 256, 0, stream>>>(h, wvec, hb, uv);

    // CSR build for all 3 edge types (bucketed two-level sort, fused edge weights)
    zero_kernel<<<1, 256, 0, stream>>>((float4*)bCnt, 80);
    bucket_hist<<<512, 256, 0, stream>>>(dsts[0], dsts[1], dsts[2], bCnt);
    bucket_scan<<<1, 384, 0, stream>>>(bCnt, bBase, gCursor, rs);
    bucket_scatter<<<3 * BPT, 256, 0, stream>>>(srcs[0], dsts[0], srcs[1], dsts[1],
                                                srcs[2], dsts[2], gCursor, binned);
    bucket_sort<<<3 * KB, 256, 0, stream>>>(binned, bBase, uv, rs, sorted, expw);

    aggregate_kernel<<<dim3(12500, 3), 256, 0, stream>>>(rs, sorted, expw, hb, hagg, den);
    msg_gemm_kernel<<<dim3(1563, 3), 256, 0, stream>>>(hagg, hb, BfN, den, cvec, msgb);
    update_gemm_kernel<<<1563, 256, 0, stream>>>(hb, msgb, BfU, bu, out);
}